// Round 3
// baseline (383.891 us; speedup 1.0000x reference)
//
#include <hip/hip_runtime.h>
#include <hip/hip_bf16.h>

typedef __attribute__((ext_vector_type(8))) short bf16x8;
typedef __attribute__((ext_vector_type(4))) float f32x4;

#define BB   64
#define LL   512
#define CIN  64
#define FF   128
#define KW   7
#define OUTL 506
#define LPAD 518        // 512 + 3 + 3
#define KC   448        // KW*CIN  (conv GEMM K)
#define KL   896        // KW*FF   (local GEMM K)
#define BK2  64         // local GEMM K-chunk staged in LDS
#define NCH2 14         // KL / BK2
#define EPSV 1e-3f

#define NPAD  (BB * LPAD * CIN)      // 2,121,728
#define PADB  (NPAD / 256)           // 8288 (exact)
#define NWT   (FF * KC)              // 57,344
#define WTB   (NWT / 256)            // 224 (exact)

#define CONVB ((BB * LL) / 64)       // 512 conv blocks
#define WARMB OUTL                   // 506 L3-warm blocks appended to conv grid
#define WARMV 2048                   // float4s warmed per block (64 rows x 128 cols)

static __device__ __forceinline__ short f2bf(float f) {
    // fp32 -> bf16, round-to-nearest-even
    unsigned u = __builtin_bit_cast(unsigned, f);
    unsigned r = (u + 0x7fffu + ((u >> 16) & 1u)) >> 16;
    return (short)r;
}

// async global->LDS, 16 B per lane; LDS dest = wave-uniform base + lane*16
static __device__ __forceinline__ void g2lds16(const float* g, float* l) {
    __builtin_amdgcn_global_load_lds(
        (const __attribute__((address_space(1))) unsigned int*)g,
        (__attribute__((address_space(3))) unsigned int*)l, 16, 0, 0);
}

// ---------------------------------------------------------------- kernel 0
// blocks [0, PADB): zero-pad x by 3 each side of L, cast bf16 -> xp (B,518,64)
// blocks [PADB, PADB+WTB): transpose+cast conv_w (448,128) -> wt[n][k] bf16
__global__ void prep_kernel(const float* __restrict__ x, const float* __restrict__ w,
                            short* __restrict__ xp, short* __restrict__ wt) {
    if (blockIdx.x < PADB) {
        int i = blockIdx.x * 256 + threadIdx.x;
        int c  = i & (CIN - 1);
        int t  = i >> 6;            // b*LPAD + lp
        int lp = t % LPAD;
        int b  = t / LPAD;
        float v = 0.0f;
        int l = lp - 3;
        if (l >= 0 && l < LL) v = x[(b * LL + l) * CIN + c];
        xp[i] = f2bf(v);
    } else {
        int i = (blockIdx.x - PADB) * 256 + threadIdx.x;  // < 57344
        int n = i / KC;
        int k = i - n * KC;
        wt[i] = f2bf(w[(size_t)k * FF + n]);
    }
}

// ---------------------------------------------------------------- kernel 1
// blocks [0, CONVB): conv-as-GEMM M=B*L, K=448, N=128 + BN1 + ReLU -> y bf16.
// blocks [CONVB, CONVB+WARMB): L3-warm the first 64 rows of each l's local_w
// slice (16 MB total) so the local kernel's first chunks hit Infinity Cache.
__global__ __launch_bounds__(256) void conv_bn_kernel(
    const short* __restrict__ xp, const short* __restrict__ wt,
    const float* __restrict__ cb, const float* __restrict__ g,
    const float* __restrict__ be, const float* __restrict__ mu,
    const float* __restrict__ va, short* __restrict__ y,
    const float* __restrict__ lw) {
    if (blockIdx.x >= CONVB) {
        // ---- L3 warm block: read-touch, keep loads live (rule 17) ----
        const int wb = blockIdx.x - CONVB;                 // 0..505
        const f32x4* src = (const f32x4*)(lw + (size_t)wb * (KL * FF));
        float s = 0.f;
        for (int i = threadIdx.x; i < WARMV; i += 256) {
            f32x4 v = src[i];
            s += v[0] + v[1] + v[2] + v[3];
        }
        asm volatile("" :: "v"(s));
        return;
    }

    const int lane = threadIdx.x & 63;
    const int wid  = threadIdx.x >> 6;
    const int m0   = blockIdx.x * 64;
    const int nb   = wid * 32;
    const int q    = lane >> 4;
    const int ln   = lane & 15;

    const short* arow[4];
#pragma unroll
    for (int mt = 0; mt < 4; ++mt) {
        int m = m0 + mt * 16 + ln;
        int b = m >> 9, l = m & 511;           // m = b*512 + l
        arow[mt] = xp + (b * LPAD + l) * CIN;  // 448 contiguous bf16 (padded)
    }
    const short* brow[2];
#pragma unroll
    for (int nt = 0; nt < 2; ++nt)
        brow[nt] = wt + (size_t)(nb + nt * 16 + ln) * KC;

    f32x4 acc[4][2];
#pragma unroll
    for (int mt = 0; mt < 4; ++mt)
#pragma unroll
        for (int nt = 0; nt < 2; ++nt) acc[mt][nt] = (f32x4){0.f, 0.f, 0.f, 0.f};

#pragma unroll 2
    for (int kc = 0; kc < KC; kc += 32) {
        const int ko = kc + q * 8;
        bf16x8 a[4], bf[2];
#pragma unroll
        for (int mt = 0; mt < 4; ++mt) a[mt] = *(const bf16x8*)(arow[mt] + ko);
#pragma unroll
        for (int nt = 0; nt < 2; ++nt) bf[nt] = *(const bf16x8*)(brow[nt] + ko);
#pragma unroll
        for (int mt = 0; mt < 4; ++mt)
#pragma unroll
            for (int nt = 0; nt < 2; ++nt)
                acc[mt][nt] = __builtin_amdgcn_mfma_f32_16x16x32_bf16(
                    a[mt], bf[nt], acc[mt][nt], 0, 0, 0);
    }

#pragma unroll
    for (int nt = 0; nt < 2; ++nt) {
        const int n = nb + nt * 16 + ln;
        const float s  = g[n] * rsqrtf(va[n] + EPSV);
        const float b2 = s * (cb[n] - mu[n]) + be[n];
#pragma unroll
        for (int mt = 0; mt < 4; ++mt) {
            const int mbase = m0 + mt * 16 + q * 4;
#pragma unroll
            for (int r = 0; r < 4; ++r) {
                float v = fmaxf(acc[mt][nt][r] * s + b2, 0.0f);
                y[(size_t)(mbase + r) * FF + n] = f2bf(v);
            }
        }
    }
}

// ---------------------------------------------------------------- kernel 2
// locally-connected, N-split: 1012 blocks = 506 l-positions x 2 column halves.
// Each block: C(64x64) = A(64x896) @ W_l(896 x cols h*64..h*64+63).
// W fp32 streamed via async global->LDS, triple-buffered BK2=64, DEPTH-2
// pipeline with counted vmcnt (T4): never drain to 0 in the main loop, so
// each chunk's HBM tail latency hides under two iterations of compute.
// Per-wave vmcnt accounting: one STAGE = 4 global_load_lds instructions; the
// A-tile global loads are consumed by their MFMAs inside the same iteration
// (compiler-inserted waitcnt before use), so at the loop-top wait the only
// outstanding VMEM is STAGE(c+1) -> s_waitcnt vmcnt(4) guarantees chunk c
// is resident without draining the prefetch.
__global__ __launch_bounds__(256) void local_bn_kernel(
    const short* __restrict__ y, const float* __restrict__ lw,
    const float* __restrict__ lb, const float* __restrict__ g,
    const float* __restrict__ be, const float* __restrict__ mu,
    const float* __restrict__ va, float* __restrict__ out) {
    __shared__ float wtile[3][BK2 * 64];       // 3 x 16 KB
    const int l    = blockIdx.x >> 1;
    const int h    = blockIdx.x & 1;           // column half
    const int lane = threadIdx.x & 63;
    const int wid  = threadIdx.x >> 6;
    const int q    = lane >> 4;
    const int ln   = lane & 15;
    const int nl   = wid * 16 + ln;            // n within this block's 64 cols

    // W source for this block: rows of 128 floats, take cols [h*64, h*64+64)
    const float* wlh = lw + (size_t)l * (KL * FF) + h * 64;

    const short* arow[4];
#pragma unroll
    for (int mt = 0; mt < 4; ++mt)
        arow[mt] = y + (size_t)(mt * 16 + ln) * (LL * FF) + (size_t)l * FF;

    f32x4 acc[4];
#pragma unroll
    for (int mt = 0; mt < 4; ++mt) acc[mt] = (f32x4){0.f, 0.f, 0.f, 0.f};

    // stage one 64x64 chunk (rows [kc, kc+64)) into buf, swizzled.
    // LDS element e = (r*4+wid)*256 + lane*4 + {0..3}  ->  row = e>>6, col' = e&63
    // source col = col' ^ ((row>>3 & 1)<<4)  (16B-aligned groups preserved)
#define STAGE(kc_, buf_)                                                        \
    {                                                                           \
        _Pragma("unroll")                                                       \
        for (int r = 0; r < 4; ++r) {                                           \
            const int ib   = (r * 4 + wid) * 256;                               \
            const int e    = ib + lane * 4;                                     \
            const int row  = e >> 6;                                            \
            const int colp = e & 63;                                            \
            const int col  = colp ^ (((row >> 3) & 1) << 4);                    \
            g2lds16(wlh + (size_t)((kc_) + row) * FF + col, &(buf_)[ib]);       \
        }                                                                       \
    }

    STAGE(0, wtile[0]);
    STAGE(BK2, wtile[1]);

    for (int c = 0; c < NCH2; ++c) {
        // chunk c resident; chunk c+1 (newest 4 VMEM) may stay in flight
        if (c < NCH2 - 1) {
            asm volatile("s_waitcnt vmcnt(4)" ::: "memory");
        } else {
            asm volatile("s_waitcnt vmcnt(0)" ::: "memory");
        }
        __builtin_amdgcn_s_barrier();          // all waves past compute(c-1)
        __builtin_amdgcn_sched_barrier(0);

        if (c + 2 < NCH2) STAGE((c + 2) * BK2, wtile[(c + 2) % 3]);

        const float* wb = wtile[c % 3];

#pragma unroll
        for (int s = 0; s < 2; ++s) {
            const int ko = c * BK2 + s * 32 + q * 8;
            bf16x8 a[4];
#pragma unroll
            for (int mt = 0; mt < 4; ++mt) a[mt] = *(const bf16x8*)(arow[mt] + ko);

            bf16x8 bfr;
#pragma unroll
            for (int j = 0; j < 8; ++j) {
                const int row = s * 32 + q * 8 + j;
                const int col = nl ^ (((row >> 3) & 1) << 4);
                bfr[j] = f2bf(wb[row * 64 + col]);
            }
#pragma unroll
            for (int mt = 0; mt < 4; ++mt)
                acc[mt] = __builtin_amdgcn_mfma_f32_16x16x32_bf16(
                    a[mt], bfr, acc[mt], 0, 0, 0);
        }
    }
#undef STAGE

    // epilogue: + local_b[l], BN2, ReLU, fp32 store
    const int n = h * 64 + nl;
    const float s  = g[n] * rsqrtf(va[n] + EPSV);
    const float b2 = s * (lb[(size_t)l * FF + n] - mu[n]) + be[n];
#pragma unroll
    for (int mt = 0; mt < 4; ++mt) {
        const int bbase = mt * 16 + q * 4;
#pragma unroll
        for (int r = 0; r < 4; ++r) {
            float v = fmaxf(acc[mt][r] * s + b2, 0.0f);
            out[(size_t)(bbase + r) * (OUTL * FF) + (size_t)l * FF + n] = v;
        }
    }
}

// ---------------------------------------------------------------- launch
extern "C" void kernel_launch(void* const* d_in, const int* in_sizes, int n_in,
                              void* d_out, int out_size, void* d_ws, size_t ws_size,
                              hipStream_t stream) {
    const float* x       = (const float*)d_in[0];
    const float* conv_w  = (const float*)d_in[1];
    const float* conv_b  = (const float*)d_in[2];
    const float* bn1_g   = (const float*)d_in[3];
    const float* bn1_b   = (const float*)d_in[4];
    const float* bn1_m   = (const float*)d_in[5];
    const float* bn1_v   = (const float*)d_in[6];
    const float* local_w = (const float*)d_in[7];
    const float* local_b = (const float*)d_in[8];
    const float* bn2_g   = (const float*)d_in[9];
    const float* bn2_b   = (const float*)d_in[10];
    const float* bn2_m   = (const float*)d_in[11];
    const float* bn2_v   = (const float*)d_in[12];
    float* out = (float*)d_out;

    short* xp  = (short*)d_ws;                   // (64, 518, 64) bf16
    short* ybf = xp + (size_t)NPAD;              // (64, 512, 128) bf16
    short* wt  = ybf + (size_t)BB * LL * FF;     // (128, 448) bf16

    prep_kernel<<<PADB + WTB, 256, 0, stream>>>(x, conv_w, xp, wt);
    conv_bn_kernel<<<CONVB + WARMB, 256, 0, stream>>>(
        xp, wt, conv_b, bn1_g, bn1_b, bn1_m, bn1_v, ybf, local_w);
    local_bn_kernel<<<2 * OUTL, 256, 0, stream>>>(
        ybf, local_w, local_b, bn2_g, bn2_b, bn2_m, bn2_v, out);
}

// Round 4
// 380.610 us; speedup vs baseline: 1.0086x; 1.0086x over previous
//
#include <hip/hip_runtime.h>
#include <hip/hip_bf16.h>

typedef __attribute__((ext_vector_type(8))) short bf16x8;
typedef __attribute__((ext_vector_type(4))) float f32x4;

#define BB   64
#define LL   512
#define CIN  64
#define FF   128
#define KW   7
#define OUTL 506
#define KC   448        // KW*CIN  (conv GEMM K)
#define KL   896        // KW*FF   (local GEMM K)
#define BK   32         // LDS K-chunk (both GEMMs)
#define NCHC 14         // KC / BK  (conv)
#define NCHL 28         // KL / BK  (local)
#define EPSV 1e-3f

#define CONVB ((BB * LL) / 64)       // 512 conv blocks

static __device__ __forceinline__ short f2bf(float f) {
    // fp32 -> bf16, round-to-nearest-even
    unsigned u = __builtin_bit_cast(unsigned, f);
    unsigned r = (u + 0x7fffu + ((u >> 16) & 1u)) >> 16;
    return (short)r;
}

// async global->LDS, 16 B per lane; LDS dest = wave-uniform base + lane*16
static __device__ __forceinline__ void g2lds16(const float* g, float* l) {
    __builtin_amdgcn_global_load_lds(
        (const __attribute__((address_space(1))) unsigned int*)g,
        (__attribute__((address_space(3))) unsigned int*)l, 16, 0, 0);
}

// ---------------------------------------------------------------- kernel 1
// conv-as-GEMM, prep folded in: M = B*L (64 rows/block), K = 448, N = 128.
// A row (b,l) = 448 CONTIGUOUS floats of x starting at (b*512 + l - 3)*64;
// out-of-range kw positions are zero-predicated per 8-float fragment (the
// fragment's 8 k-values always lie within one kw => one bounds test each).
// W: conv_w (448x128 fp32) staged per block in BK=32-row chunks via async
// global->LDS, double-buffered (2 x 16 KB), fragments built with f2bf.
// Numerics identical to the previous prep+conv pair (same f2bf->MFMA path).
__global__ __launch_bounds__(256) void conv_bn_kernel(
    const float* __restrict__ x, const float* __restrict__ cw,
    const float* __restrict__ cb, const float* __restrict__ g,
    const float* __restrict__ be, const float* __restrict__ mu,
    const float* __restrict__ va, short* __restrict__ y) {
    __shared__ float wchunk[2][BK * FF];       // 2 x 16 KB
    const int lane = threadIdx.x & 63;
    const int wid  = threadIdx.x >> 6;
    const int m0   = blockIdx.x * 64;
    const int nb   = wid * 32;
    const int q    = lane >> 4;
    const int ln   = lane & 15;

    const float* xbase[4];
    int lrow[4];
#pragma unroll
    for (int mt = 0; mt < 4; ++mt) {
        int m = m0 + mt * 16 + ln;
        int b = m >> 9, l = m & 511;                    // m = b*512 + l
        lrow[mt]  = l;
        xbase[mt] = x + (long)((b << 9) + l - 3) * CIN; // row start (may pre-date x; only deref'd when valid)
    }

    f32x4 acc[4][2];
#pragma unroll
    for (int mt = 0; mt < 4; ++mt)
#pragma unroll
        for (int nt = 0; nt < 2; ++nt) acc[mt][nt] = (f32x4){0.f, 0.f, 0.f, 0.f};

    // stage conv_w rows [kc, kc+32) (16 KB contiguous fp32) into buf, linear
#define STAGEW(kc_, buf_)                                                      \
    {                                                                          \
        _Pragma("unroll")                                                      \
        for (int r = 0; r < 4; ++r) {                                          \
            const int ib = (r * 4 + wid) * 256;                                \
            g2lds16(cw + (size_t)(kc_) * FF + ib + lane * 4, &(buf_)[ib]);     \
        }                                                                      \
    }

    STAGEW(0, wchunk[0]);

    for (int c = 0; c < NCHC; ++c) {
        __syncthreads();                       // drains vmcnt -> chunk c resident
        if (c + 1 < NCHC) STAGEW((c + 1) * BK, wchunk[(c + 1) & 1]);
        const float* wb = wchunk[c & 1];

        const int ko = c * BK + q * 8;
        const int kw = ko >> 6;                // uniform over the 8-frag (8|ko)

        bf16x8 a[4];
#pragma unroll
        for (int mt = 0; mt < 4; ++mt) {
            const bool v = (unsigned)(lrow[mt] - 3 + kw) < (unsigned)LL;
            f32x4 lo = v ? *(const f32x4*)(xbase[mt] + ko)     : (f32x4){0.f, 0.f, 0.f, 0.f};
            f32x4 hi = v ? *(const f32x4*)(xbase[mt] + ko + 4) : (f32x4){0.f, 0.f, 0.f, 0.f};
#pragma unroll
            for (int j = 0; j < 4; ++j) {
                a[mt][j]     = f2bf(lo[j]);
                a[mt][j + 4] = f2bf(hi[j]);
            }
        }

        bf16x8 bf[2];
#pragma unroll
        for (int nt = 0; nt < 2; ++nt) {
            const int n = nb + nt * 16 + ln;
#pragma unroll
            for (int j = 0; j < 8; ++j)
                bf[nt][j] = f2bf(wb[(q * 8 + j) * FF + n]);
        }
#pragma unroll
        for (int mt = 0; mt < 4; ++mt)
#pragma unroll
            for (int nt = 0; nt < 2; ++nt)
                acc[mt][nt] = __builtin_amdgcn_mfma_f32_16x16x32_bf16(
                    a[mt], bf[nt], acc[mt][nt], 0, 0, 0);
    }
#undef STAGEW

#pragma unroll
    for (int nt = 0; nt < 2; ++nt) {
        const int n = nb + nt * 16 + ln;
        const float s  = g[n] * rsqrtf(va[n] + EPSV);
        const float b2 = s * (cb[n] - mu[n]) + be[n];
#pragma unroll
        for (int mt = 0; mt < 4; ++mt) {
            const int mbase = m0 + mt * 16 + q * 4;
#pragma unroll
            for (int r = 0; r < 4; ++r) {
                float v = fmaxf(acc[mt][nt][r] * s + b2, 0.0f);
                y[(size_t)(mbase + r) * FF + n] = f2bf(v);
            }
        }
    }
}

// ---------------------------------------------------------------- kernel 2
// locally-connected: one block per l (exact round-0 version — best measured).
// C(64x128) = A(64x896) @ W_l(896x128). W_l fp32 streamed via async
// global->LDS (16 B/lane), double-buffered BK=32.
__global__ __launch_bounds__(256) void local_bn_kernel(
    const short* __restrict__ y, const float* __restrict__ lw,
    const float* __restrict__ lb, const float* __restrict__ g,
    const float* __restrict__ be, const float* __restrict__ mu,
    const float* __restrict__ va, float* __restrict__ out) {
    __shared__ float wtile[2][BK * FF];        // 2 x 16 KB
    const int l    = blockIdx.x;
    const int lane = threadIdx.x & 63;
    const int wid  = threadIdx.x >> 6;
    const int nb   = wid * 32;
    const int q    = lane >> 4;
    const int ln   = lane & 15;

    const float* wl = lw + (size_t)l * (KL * FF);

    const short* arow[4];
#pragma unroll
    for (int mt = 0; mt < 4; ++mt)
        arow[mt] = y + (size_t)(mt * 16 + ln) * (LL * FF) + (size_t)l * FF;

    f32x4 acc[4][2];
#pragma unroll
    for (int mt = 0; mt < 4; ++mt)
#pragma unroll
        for (int nt = 0; nt < 2; ++nt) acc[mt][nt] = (f32x4){0.f, 0.f, 0.f, 0.f};

    // stage chunk 0
    {
        const float* src = wl;
#pragma unroll
        for (int r = 0; r < 4; ++r)
            g2lds16(src + (size_t)(r * 256 + wid * 64 + lane) * 4,
                    &wtile[0][(r * 256 + wid * 64) * 4]);
    }

    for (int c = 0; c < NCHL; ++c) {
        __syncthreads();                       // drains vmcnt -> chunk c resident
        if (c + 1 < NCHL) {                    // prefetch chunk c+1 into other buf
            const float* src = wl + (size_t)(c + 1) * (BK * FF);
            float* dst = wtile[(c + 1) & 1];
#pragma unroll
            for (int r = 0; r < 4; ++r)
                g2lds16(src + (size_t)(r * 256 + wid * 64 + lane) * 4,
                        &dst[(r * 256 + wid * 64) * 4]);
        }
        const float* wb = wtile[c & 1];
        const int ko = c * BK + q * 8;

        bf16x8 a[4];
#pragma unroll
        for (int mt = 0; mt < 4; ++mt) a[mt] = *(const bf16x8*)(arow[mt] + ko);

        bf16x8 bf[2];
#pragma unroll
        for (int nt = 0; nt < 2; ++nt) {
            const int n = nb + nt * 16 + ln;
#pragma unroll
            for (int j = 0; j < 8; ++j)
                bf[nt][j] = f2bf(wb[(q * 8 + j) * FF + n]);
        }
#pragma unroll
        for (int mt = 0; mt < 4; ++mt)
#pragma unroll
            for (int nt = 0; nt < 2; ++nt)
                acc[mt][nt] = __builtin_amdgcn_mfma_f32_16x16x32_bf16(
                    a[mt], bf[nt], acc[mt][nt], 0, 0, 0);
    }

    // epilogue: + local_b[l], BN2, ReLU, fp32 store
#pragma unroll
    for (int nt = 0; nt < 2; ++nt) {
        const int n = nb + nt * 16 + ln;
        const float s  = g[n] * rsqrtf(va[n] + EPSV);
        const float b2 = s * (lb[(size_t)l * FF + n] - mu[n]) + be[n];
#pragma unroll
        for (int mt = 0; mt < 4; ++mt) {
            const int bbase = mt * 16 + q * 4;
#pragma unroll
            for (int r = 0; r < 4; ++r) {
                float v = fmaxf(acc[mt][nt][r] * s + b2, 0.0f);
                out[(size_t)(bbase + r) * (OUTL * FF) + (size_t)l * FF + n] = v;
            }
        }
    }
}

// ---------------------------------------------------------------- launch
extern "C" void kernel_launch(void* const* d_in, const int* in_sizes, int n_in,
                              void* d_out, int out_size, void* d_ws, size_t ws_size,
                              hipStream_t stream) {
    const float* x       = (const float*)d_in[0];
    const float* conv_w  = (const float*)d_in[1];
    const float* conv_b  = (const float*)d_in[2];
    const float* bn1_g   = (const float*)d_in[3];
    const float* bn1_b   = (const float*)d_in[4];
    const float* bn1_m   = (const float*)d_in[5];
    const float* bn1_v   = (const float*)d_in[6];
    const float* local_w = (const float*)d_in[7];
    const float* local_b = (const float*)d_in[8];
    const float* bn2_g   = (const float*)d_in[9];
    const float* bn2_b   = (const float*)d_in[10];
    const float* bn2_m   = (const float*)d_in[11];
    const float* bn2_v   = (const float*)d_in[12];
    float* out = (float*)d_out;

    short* ybf = (short*)d_ws;                   // (64, 512, 128) bf16

    conv_bn_kernel<<<CONVB, 256, 0, stream>>>(
        x, conv_w, conv_b, bn1_g, bn1_b, bn1_m, bn1_v, ybf);
    local_bn_kernel<<<OUTL, 256, 0, stream>>>(
        ybf, local_w, local_b, bn2_g, bn2_b, bn2_m, bn2_v, out);
}